// Round 8
// baseline (9704.312 us; speedup 1.0000x reference)
//
#include <hip/hip_runtime.h>
#include <hip/hip_fp16.h>

#define DEVINL __device__ __forceinline__

constexpr int B = 256, S = 512;
constexpr int H0 = 64, H1 = 128, H2 = 256;

typedef _Float16 f16x8 __attribute__((ext_vector_type(8)));
typedef float f32x4 __attribute__((ext_vector_type(4)));
typedef _Float16 h2v __attribute__((ext_vector_type(2)));

DEVINL float fexp2(float x) { return __builtin_amdgcn_exp2f(x); }
DEVINL float frcp(float x) { return __builtin_amdgcn_rcpf(x); }
DEVINL float fsig(float x) { return frcp(1.f + fexp2(-1.44269504088896f * x)); }
DEVINL float ftanh_(float x) { return 1.f - 2.f * frcp(1.f + fexp2(2.88539008177793f * x)); }
DEVINL h2v as_h2(unsigned u) { union { unsigned u; h2v h; } x; x.u = u; return x.h; }
DEVINL float fdot2(unsigned a, unsigned b, float c) {
  return __builtin_amdgcn_fdot2(as_h2(a), as_h2(b), c, false);
}
union FU { uint4 u; f16x8 h; };
DEVINL f16x8 as_f16x8(uint4 u) { FU x; x.u = u; return x.h; }

DEVINL void pin(uint4& v) {
  asm volatile("" : "+v"(v.x), "+v"(v.y), "+v"(v.z), "+v"(v.w));
}
// LDS-only workgroup barrier: no vmcnt drain, global ops stay in flight.
DEVINL void wg_barrier() {
  asm volatile("s_waitcnt lgkmcnt(0)" ::: "memory");
  __builtin_amdgcn_s_barrier();
  asm volatile("" ::: "memory");
}
DEVINL void vm_drain() { asm volatile("s_waitcnt vmcnt(0)" ::: "memory"); }

// Row permutation: r' = mt*16 + quad*4 + reg -> channel = r'>>2, gate = r'&3.
// orig torch row = gate*Hch + channel. One C-frag lane holds one channel's
// (i,f,g,o) quad (C: col=lane&15, row=(lane>>4)*4+reg).

// All six weight-fragment packs in one dispatch (grid.y = job).
__global__ __launch_bounds__(256) void pack_all(
    const float* __restrict__ s0, const float* __restrict__ s1,
    const float* __restrict__ s2, const float* __restrict__ s3,
    const float* __restrict__ s4, const float* __restrict__ s5,
    uint4* __restrict__ d0, uint4* __restrict__ d1, uint4* __restrict__ d2,
    uint4* __restrict__ d3, uint4* __restrict__ d4, uint4* __restrict__ d5) {
  const float* src; uint4* dst; int Hch, Kdim, MT, KT;
  switch (blockIdx.y) {
    case 0: src = s0; dst = d0; Hch = 64;  Kdim = 64;  MT = 16; KT = 2; break;
    case 1: src = s1; dst = d1; Hch = 128; Kdim = 128; MT = 32; KT = 4; break;
    case 2: src = s2; dst = d2; Hch = 256; Kdim = 256; MT = 64; KT = 8; break;
    case 3: src = s3; dst = d3; Hch = 64;  Kdim = 32;  MT = 16; KT = 1; break;
    case 4: src = s4; dst = d4; Hch = 128; Kdim = 64;  MT = 32; KT = 2; break;
    default: src = s5; dst = d5; Hch = 256; Kdim = 128; MT = 64; KT = 4; break;
  }
  int o = blockIdx.x * 256 + threadIdx.x;
  if (o >= MT * KT * 64) return;
  int lane = o & 63, fk = o >> 6;
  int kt = fk % KT, mt = fk / KT;
  int rp = mt * 16 + (lane & 15);
  int orig = (rp & 3) * Hch + (rp >> 2);
  int k0 = kt * 32 + (lane >> 4) * 8;
  unsigned r[4];
#pragma unroll
  for (int p = 0; p < 4; ++p) {
    unsigned lo = __half_as_ushort(__float2half_rn(src[(size_t)orig * Kdim + k0 + 2 * p]));
    unsigned hi = __half_as_ushort(__float2half_rn(src[(size_t)orig * Kdim + k0 + 2 * p + 1]));
    r[p] = lo | (hi << 16);
  }
  uint4 v; v.x = r[0]; v.y = r[1]; v.z = r[2]; v.w = r[3];
  dst[o] = v;
}

// Bias sums (3 layers) + packed Wl in one dispatch.
__global__ __launch_bounds__(256) void pack_misc(
    const float* __restrict__ bih0, const float* __restrict__ bhh0, float* __restrict__ bs0,
    const float* __restrict__ bih1, const float* __restrict__ bhh1, float* __restrict__ bs1,
    const float* __restrict__ bih2, const float* __restrict__ bhh2, float* __restrict__ bs2,
    const float* __restrict__ wl, unsigned* __restrict__ wlp) {
  int i = blockIdx.x * 256 + threadIdx.x;
  if (i < 256) {
    int orig = (i & 3) * 64 + (i >> 2);
    bs0[i] = bih0[orig] + bhh0[orig];
  } else if (i < 768) {
    int r = i - 256, orig = (r & 3) * 128 + (r >> 2);
    bs1[r] = bih1[orig] + bhh1[orig];
  } else if (i < 1792) {
    int r = i - 768, orig = (r & 3) * 256 + (r >> 2);
    bs2[r] = bih2[orig] + bhh2[orig];
  } else if (i < 1920) {
    int r = i - 1792;
    unsigned lo = __half_as_ushort(__float2half_rn(wl[2 * r]));
    unsigned hi = __half_as_ushort(__float2half_rn(wl[2 * r + 1]));
    wlp[r] = lo | (hi << 16);
  }
}

__global__ __launch_bounds__(256) void f2h(const float* __restrict__ x,
                                           __half* __restrict__ y, int n8) {
  int i = blockIdx.x * 256 + threadIdx.x;
  if (i >= n8) return;
  float4 a = *(const float4*)(x + i * 8);
  float4 b = *(const float4*)(x + i * 8 + 4);
  __half h[8];
  h[0] = __float2half_rn(a.x); h[1] = __float2half_rn(a.y);
  h[2] = __float2half_rn(a.z); h[3] = __float2half_rn(a.w);
  h[4] = __float2half_rn(b.x); h[5] = __float2half_rn(b.y);
  h[6] = __float2half_rn(b.z); h[7] = __float2half_rn(b.w);
  *(uint4*)(y + i * 8) = *(const uint4*)h;
}

// MFMA input GEMM -> preT in C-frag layout.
template <int KT>
__global__ __launch_bounds__(256) __attribute__((amdgpu_waves_per_eu(4, 4)))
void ingemm_mfma(const __half* __restrict__ x,
    const uint4* __restrict__ wp, const float* __restrict__ bs,
    f32x4* __restrict__ preT, int MT, int Sc, int t0) {
  constexpr int K = KT * 32;
  const int tid = threadIdx.x, w = tid >> 6, lane = tid & 63;
  const int n16 = lane & 15, quad = lane >> 4;
  const int bt = blockIdx.x, b0 = bt * 16;
  const int tlb = blockIdx.y * 8;
  const int mb = blockIdx.z * 16;

  uint4 areg[4][KT];
#pragma unroll
  for (int im = 0; im < 4; ++im)
#pragma unroll
    for (int kt = 0; kt < KT; ++kt) {
      areg[im][kt] = wp[((size_t)(mb + w * 4 + im) * KT + kt) * 64 + lane];
      pin(areg[im][kt]);
    }
  f32x4 bini[4];
#pragma unroll
  for (int im = 0; im < 4; ++im)
    bini[im] = *(const f32x4*)(bs + (mb + w * 4 + im) * 16 + quad * 4);

  for (int tt = 0; tt < 8; ++tt) {
    int t = t0 + tlb + tt;
    const __half* xr = x + ((size_t)(b0 + n16) * S + t) * K + quad * 8;
    uint4 bfr[KT];
#pragma unroll
    for (int kt = 0; kt < KT; ++kt) bfr[kt] = *(const uint4*)(xr + kt * 32);
    f32x4 acc[4];
#pragma unroll
    for (int im = 0; im < 4; ++im) acc[im] = bini[im];
#pragma unroll
    for (int kt = 0; kt < KT; ++kt)
#pragma unroll
      for (int im = 0; im < 4; ++im)
        acc[im] = __builtin_amdgcn_mfma_f32_16x16x32_f16(as_f16x8(areg[im][kt]),
                                                         as_f16x8(bfr[kt]), acc[im], 0, 0, 0);
#pragma unroll
    for (int im = 0; im < 4; ++im)
      preT[((size_t)(bt * Sc + tlb + tt) * MT + mb + w * 4 + im) * 64 + lane] = acc[im];
  }
}

// Single-WG weight-stationary scan (layers 0/1). 16 WGs x 16 batch, 512 thr.
template <int H>
__global__ __launch_bounds__(512) __attribute__((amdgpu_waves_per_eu(2, 2)))
void scan_s1(const uint4* __restrict__ wp, const f32x4* __restrict__ preT,
             __half* __restrict__ xout, float* __restrict__ sth,
             float* __restrict__ stc, int Sc, int t0, int first) {
  constexpr int MT = H / 4;
  constexpr int MTW = MT / 8;
  constexpr int KT = H / 32;
  constexpr int HP = H + 8;
  __shared__ __half hbo[2][16 * HP];
  const int tid = threadIdx.x, w = tid >> 6, lane = tid & 63;
  const int n16 = lane & 15, quad = lane >> 4;
  const int bt = blockIdx.x, b0 = bt * 16;

  uint4 areg[MTW][KT];
#pragma unroll
  for (int im = 0; im < MTW; ++im)
#pragma unroll
    for (int kt = 0; kt < KT; ++kt) {
      areg[im][kt] = wp[((size_t)(w * MTW + im) * KT + kt) * 64 + lane];
      pin(areg[im][kt]);
    }

  float cst[MTW];
#pragma unroll
  for (int im = 0; im < MTW; ++im) {
    int ch = (w * MTW + im) * 4 + quad;
    cst[im] = first ? 0.f : stc[(size_t)(b0 + n16) * H + ch];
  }
  {
    int pi = (t0 - 1) & 1;
    for (int i = tid; i < 16 * H; i += 512) {
      int n = i / H, c = i % H;
      hbo[pi][n * HP + c] = first ? __float2half_rn(0.f)
                                  : __float2half_rn(sth[(size_t)(b0 + n) * H + c]);
    }
  }
  __syncthreads();

  f32x4 nxt[MTW];
#pragma unroll
  for (int im = 0; im < MTW; ++im)
    nxt[im] = preT[((size_t)(bt * Sc) * MT + w * MTW + im) * 64 + lane];

  for (int tl = 0; tl < Sc; ++tl) {
    const int s = t0 + tl;
    const int pw = s & 1, pbl = pw ^ 1;
    f32x4 acc[MTW];
#pragma unroll
    for (int im = 0; im < MTW; ++im) acc[im] = nxt[im];
    if (tl + 1 < Sc) {
#pragma unroll
      for (int im = 0; im < MTW; ++im)
        nxt[im] = preT[((size_t)(bt * Sc + tl + 1) * MT + w * MTW + im) * 64 + lane];
    }

#pragma unroll
    for (int kt = 0; kt < KT; ++kt) {
      uint4 bf = *(const uint4*)&hbo[pbl][n16 * HP + kt * 32 + quad * 8];
#pragma unroll
      for (int im = 0; im < MTW; ++im)
        acc[im] = __builtin_amdgcn_mfma_f32_16x16x32_f16(as_f16x8(areg[im][kt]),
                                                         as_f16x8(bf), acc[im], 0, 0, 0);
    }

    if (tl > 0 && tid < 16 * (H / 8)) {
      int n = tid / (H / 8), kq = tid % (H / 8);
      uint4 v = *(const uint4*)&hbo[pbl][n * HP + kq * 8];
      *(uint4*)(xout + ((size_t)(b0 + n) * S + (s - 1)) * H + kq * 8) = v;
    }

#pragma unroll
    for (int im = 0; im < MTW; ++im) {
      float gi = fsig(acc[im][0]);
      float gf = fsig(acc[im][1]);
      float gg = ftanh_(acc[im][2]);
      float go = fsig(acc[im][3]);
      float cn = gf * cst[im] + gi * gg;
      cst[im] = cn;
      hbo[pw][n16 * HP + (w * MTW + im) * 4 + quad] = __float2half_rn(go * ftanh_(cn));
    }
    wg_barrier();
  }

  {
    const int sl = t0 + Sc - 1, pl = sl & 1;
    if (tid < 16 * (H / 8)) {
      int n = tid / (H / 8), kq = tid % (H / 8);
      uint4 v = *(const uint4*)&hbo[pl][n * HP + kq * 8];
      *(uint4*)(xout + ((size_t)(b0 + n) * S + sl) * H + kq * 8) = v;
    }
    for (int i = tid; i < 16 * H; i += 512) {
      int n = i / H, c = i % H;
      sth[(size_t)(b0 + n) * H + c] = __half2float(hbo[pl][n * HP + c]);
    }
#pragma unroll
    for (int im = 0; im < MTW; ++im) {
      int ch = (w * MTW + im) * 4 + quad;
      stc[(size_t)(b0 + n16) * H + ch] = cst[im];
    }
  }
}

// Layer-2 scan, decentralized exchange. 16 WGs = 8 batch groups (32 cols) x 2
// m-halves; 1024 thr (16 waves, 4/EU). Per wave: 2 m-tiles x 2 col-tiles;
// weights aown/apeer statically indexed + pinned (64 VGPR).
// Per step: ONE LDS barrier. Every wave imports peer B-frags directly
// global->register (relaxed 8B atomics, LLC-coherent). Export by waves 12-15
// from LDS; each drains vmcnt then atomic-incs a 128B-padded counter
// (monotonic 4*(t+1)); pollers wait cnt >= 4*s. Fused final linear reuses the
// imported peer frags from registers.
__global__ __launch_bounds__(1024) __attribute__((amdgpu_waves_per_eu(4, 4)))
void scan2_pair(const uint4* __restrict__ wp, const f32x4* __restrict__ preT,
                float* __restrict__ out, const unsigned* __restrict__ wlp,
                const float* __restrict__ blp, float* __restrict__ sth,
                float* __restrict__ stc, unsigned long long* __restrict__ xh,
                int* __restrict__ cnt, int Sc, int t0, int first) {
  constexpr int HP = 136;  // own-half row: 128 ch + pad (halves)
  __shared__ __half hb[2][32 * HP];
  __shared__ unsigned wls[128];

  const int tid = threadIdx.x, w = tid >> 6, lane = tid & 63;
  const int n16 = lane & 15, quad = lane >> 4;
  const int bt = blockIdx.x & 7, half = blockIdx.x >> 3;
  const int phalf = 1 - half;
  const int b0 = bt * 32;
  const int gm0 = half * 32 + w * 2;  // global m-tile of this wave
  const int lm0 = w * 2;              // local (own-half) m-tile
  int* cown = cnt + (bt * 2 + half) * 32;    // 128B-padded counters
  int* cpeer = cnt + (bt * 2 + phalf) * 32;

  uint4 aown[2][4], apeer[2][4];
#pragma unroll
  for (int im = 0; im < 2; ++im)
#pragma unroll
    for (int ktl = 0; ktl < 4; ++ktl) {
      aown[im][ktl] = wp[((size_t)(gm0 + im) * 8 + half * 4 + ktl) * 64 + lane];
      pin(aown[im][ktl]);
      apeer[im][ktl] = wp[((size_t)(gm0 + im) * 8 + phalf * 4 + ktl) * 64 + lane];
      pin(apeer[im][ktl]);
    }
  for (int i = tid; i < 128; i += 1024) wls[i] = wlp[i];

  float cst[2][2];
#pragma unroll
  for (int im = 0; im < 2; ++im)
#pragma unroll
    for (int ct = 0; ct < 2; ++ct) {
      int ch = (gm0 + im) * 4 + quad;
      cst[im][ct] = first ? 0.f : stc[(size_t)(b0 + ct * 16 + n16) * 256 + ch];
    }
  {
    int pi = (t0 - 1) & 1;
    for (int i = tid; i < 32 * 128; i += 1024) {
      int col = i >> 7, c = i & 127;
      hb[pi][col * HP + c] =
          first ? __float2half_rn(0.f)
                : __float2half_rn(sth[(size_t)(b0 + col) * 256 + half * 128 + c]);
    }
  }
  __syncthreads();

  const float bl0 = blp[0];

  for (int tl = 0; tl < Sc; ++tl) {
    const int s = t0 + tl;
    const int pw = s & 1, pbl = pw ^ 1;

    // 1) issue this step's preT loads (complete during the poll below)
    f32x4 acc[2][2];
#pragma unroll
    for (int im = 0; im < 2; ++im)
#pragma unroll
      for (int ct = 0; ct < 2; ++ct)
        acc[im][ct] =
            preT[(((size_t)(2 * bt + ct) * Sc + tl) * 64 + gm0 + im) * 64 + lane];

    // 2) peer import: every wave loads its own peer B-frags from LLC
    uint4 bp[2][4];
    if (first && tl == 0) {
#pragma unroll
      for (int ct = 0; ct < 2; ++ct)
#pragma unroll
        for (int ktl = 0; ktl < 4; ++ktl) bp[ct][ktl] = make_uint4(0, 0, 0, 0);
    } else {
      while (__hip_atomic_load(cpeer, __ATOMIC_RELAXED, __HIP_MEMORY_SCOPE_AGENT) < 4 * s)
        __builtin_amdgcn_s_sleep(1);
      const unsigned long long* src =
          xh + ((size_t)(pbl * 8 + bt) * 2 + phalf) * 1024;
#pragma unroll
      for (int ct = 0; ct < 2; ++ct)
#pragma unroll
        for (int ktl = 0; ktl < 4; ++ktl) {
          int idx = (ct * 16 + n16) * 32 + ktl * 8 + quad * 2;
          unsigned long long lo = __hip_atomic_load(src + idx, __ATOMIC_RELAXED,
                                                    __HIP_MEMORY_SCOPE_AGENT);
          unsigned long long hi = __hip_atomic_load(src + idx + 1, __ATOMIC_RELAXED,
                                                    __HIP_MEMORY_SCOPE_AGENT);
          uint4 v;
          v.x = (unsigned)lo; v.y = (unsigned)(lo >> 32);
          v.z = (unsigned)hi; v.w = (unsigned)(hi >> 32);
          bp[ct][ktl] = v;
        }
    }
#pragma unroll
    for (int ktl = 0; ktl < 4; ++ktl)
#pragma unroll
      for (int ct = 0; ct < 2; ++ct)
#pragma unroll
        for (int im = 0; im < 2; ++im)
          acc[im][ct] = __builtin_amdgcn_mfma_f32_16x16x32_f16(
              as_f16x8(apeer[im][ktl]), as_f16x8(bp[ct][ktl]), acc[im][ct], 0, 0, 0);

    // 3) own-half MFMA from LDS
#pragma unroll
    for (int ktl = 0; ktl < 4; ++ktl)
#pragma unroll
      for (int ct = 0; ct < 2; ++ct) {
        uint4 bf = *(const uint4*)&hb[pbl][(ct * 16 + n16) * HP + ktl * 32 + quad * 8];
#pragma unroll
        for (int im = 0; im < 2; ++im)
          acc[im][ct] = __builtin_amdgcn_mfma_f32_16x16x32_f16(
              as_f16x8(aown[im][ktl]), as_f16x8(bf), acc[im][ct], 0, 0, 0);
      }

    // 4) fused final linear for step s-1 (own from LDS, peer from bp regs)
    if (half == 0 && w == 2 && tl > 0) {
      float sd0 = 0.f, sd1 = 0.f;
#pragma unroll
      for (int ktl = 0; ktl < 4; ++ktl) {
        uint4 bo0 = *(const uint4*)&hb[pbl][n16 * HP + ktl * 32 + quad * 8];
        uint4 bo1 = *(const uint4*)&hb[pbl][(16 + n16) * HP + ktl * 32 + quad * 8];
        const unsigned* o0 = (const unsigned*)&bo0;
        const unsigned* o1 = (const unsigned*)&bo1;
        const unsigned* p0 = (const unsigned*)&bp[0][ktl];
        const unsigned* p1 = (const unsigned*)&bp[1][ktl];
#pragma unroll
        for (int p = 0; p < 4; ++p) {
          int oi = ktl * 16 + quad * 4 + p;        // own pairs (half==0)
          int pi2 = 64 + ktl * 16 + quad * 4 + p;  // peer pairs
          sd0 = fdot2(o0[p], wls[oi], sd0);
          sd1 = fdot2(o1[p], wls[oi], sd1);
          sd0 = fdot2(p0[p], wls[pi2], sd0);
          sd1 = fdot2(p1[p], wls[pi2], sd1);
        }
      }
      sd0 += __shfl_xor(sd0, 16); sd0 += __shfl_xor(sd0, 32);
      sd1 += __shfl_xor(sd1, 16); sd1 += __shfl_xor(sd1, 32);
      if (lane < 16) {
        out[(size_t)(b0 + lane) * S + (s - 1)] = ftanh_(sd0 + bl0);
        out[(size_t)(b0 + 16 + lane) * S + (s - 1)] = ftanh_(sd1 + bl0);
      }
    }

    // 5) gates + own-half LDS write
#pragma unroll
    for (int im = 0; im < 2; ++im)
#pragma unroll
      for (int ct = 0; ct < 2; ++ct) {
        float gi = fsig(acc[im][ct][0]);
        float gf = fsig(acc[im][ct][1]);
        float gg = ftanh_(acc[im][ct][2]);
        float go = fsig(acc[im][ct][3]);
        float cn = gf * cst[im][ct] + gi * gg;
        cst[im][ct] = cn;
        hb[pw][(ct * 16 + n16) * HP + (lm0 + im) * 4 + quad] =
            __float2half_rn(go * ftanh_(cn));
      }
    wg_barrier();  // the ONLY per-step barrier

    // 6) export (waves 12..15): LDS -> xh, drain, counter inc
    if (w >= 12) {
      int ew = w - 12;
      unsigned long long* dst = xh + ((size_t)(pw * 8 + bt) * 2 + half) * 1024;
#pragma unroll
      for (int j = 0; j < 4; ++j) {
        int e = j * 64 + lane;
        int col = ew * 8 + (e >> 5), chunk = e & 31;
        unsigned long long v = *(const unsigned long long*)&hb[pw][col * HP + chunk * 4];
        __hip_atomic_store(dst + col * 32 + chunk, v, __ATOMIC_RELAXED,
                           __HIP_MEMORY_SCOPE_AGENT);
      }
      vm_drain();
      if (lane == 0)
        __hip_atomic_fetch_add(cown, 1, __ATOMIC_RELAXED, __HIP_MEMORY_SCOPE_AGENT);
    }
  }

  // ---- tail: out(sl) (fresh peer import) + state carry
  {
    const int sl = t0 + Sc - 1, pl = sl & 1;
    if (half == 0 && w == 2) {
      while (__hip_atomic_load(cpeer, __ATOMIC_RELAXED, __HIP_MEMORY_SCOPE_AGENT) <
             4 * (sl + 1))
        __builtin_amdgcn_s_sleep(1);
      const unsigned long long* src = xh + ((size_t)(pl * 8 + bt) * 2 + phalf) * 1024;
      float sd0 = 0.f, sd1 = 0.f;
#pragma unroll
      for (int ktl = 0; ktl < 4; ++ktl) {
        uint4 bo0 = *(const uint4*)&hb[pl][n16 * HP + ktl * 32 + quad * 8];
        uint4 bo1 = *(const uint4*)&hb[pl][(16 + n16) * HP + ktl * 32 + quad * 8];
        uint4 bpv[2];
#pragma unroll
        for (int ct = 0; ct < 2; ++ct) {
          int idx = (ct * 16 + n16) * 32 + ktl * 8 + quad * 2;
          unsigned long long lo = __hip_atomic_load(src + idx, __ATOMIC_RELAXED,
                                                    __HIP_MEMORY_SCOPE_AGENT);
          unsigned long long hi = __hip_atomic_load(src + idx + 1, __ATOMIC_RELAXED,
                                                    __HIP_MEMORY_SCOPE_AGENT);
          bpv[ct].x = (unsigned)lo; bpv[ct].y = (unsigned)(lo >> 32);
          bpv[ct].z = (unsigned)hi; bpv[ct].w = (unsigned)(hi >> 32);
        }
        const unsigned* o0 = (const unsigned*)&bo0;
        const unsigned* o1 = (const unsigned*)&bo1;
        const unsigned* p0 = (const unsigned*)&bpv[0];
        const unsigned* p1 = (const unsigned*)&bpv[1];
#pragma unroll
        for (int p = 0; p < 4; ++p) {
          int oi = ktl * 16 + quad * 4 + p;
          int pi2 = 64 + ktl * 16 + quad * 4 + p;
          sd0 = fdot2(o0[p], wls[oi], sd0);
          sd1 = fdot2(o1[p], wls[oi], sd1);
          sd0 = fdot2(p0[p], wls[pi2], sd0);
          sd1 = fdot2(p1[p], wls[pi2], sd1);
        }
      }
      sd0 += __shfl_xor(sd0, 16); sd0 += __shfl_xor(sd0, 32);
      sd1 += __shfl_xor(sd1, 16); sd1 += __shfl_xor(sd1, 32);
      if (lane < 16) {
        out[(size_t)(b0 + lane) * S + sl] = ftanh_(sd0 + bl0);
        out[(size_t)(b0 + 16 + lane) * S + sl] = ftanh_(sd1 + bl0);
      }
    }
    for (int i = tid; i < 32 * 128; i += 1024) {
      int col = i >> 7, c = i & 127;
      sth[(size_t)(b0 + col) * 256 + half * 128 + c] = __half2float(hb[pl][col * HP + c]);
    }
#pragma unroll
    for (int im = 0; im < 2; ++im)
#pragma unroll
      for (int ct = 0; ct < 2; ++ct) {
        int ch = (gm0 + im) * 4 + quad;
        stc[(size_t)(b0 + ct * 16 + n16) * 256 + ch] = cst[im][ct];
      }
  }
}

extern "C" void kernel_launch(void* const* d_in, const int* in_sizes, int n_in,
                              void* d_out, int out_size, void* d_ws, size_t ws_size,
                              hipStream_t stream) {
  (void)in_sizes; (void)n_in; (void)out_size;
  const float* noise = (const float*)d_in[0];
  const float* Wih0 = (const float*)d_in[1];
  const float* Whh0 = (const float*)d_in[2];
  const float* bih0 = (const float*)d_in[3];
  const float* bhh0 = (const float*)d_in[4];
  const float* Wih1 = (const float*)d_in[5];
  const float* Whh1 = (const float*)d_in[6];
  const float* bih1 = (const float*)d_in[7];
  const float* bhh1 = (const float*)d_in[8];
  const float* Wih2 = (const float*)d_in[9];
  const float* Whh2 = (const float*)d_in[10];
  const float* bih2 = (const float*)d_in[11];
  const float* bhh2 = (const float*)d_in[12];
  const float* Wl = (const float*)d_in[13];
  const float* bl = (const float*)d_in[14];
  float* out = (float*)d_out;

  char* p = (char*)d_ws;
  auto alloc = [&](size_t bytes) {
    char* r = p;
    p += (bytes + 255) & ~(size_t)255;
    return r;
  };
  uint4* wpH0 = (uint4*)alloc((size_t)16 * 2 * 1024);
  uint4* wpH1 = (uint4*)alloc((size_t)32 * 4 * 1024);
  uint4* wpH2 = (uint4*)alloc((size_t)64 * 8 * 1024);
  uint4* wpI0 = (uint4*)alloc((size_t)16 * 1 * 1024);
  uint4* wpI1 = (uint4*)alloc((size_t)32 * 2 * 1024);
  uint4* wpI2 = (uint4*)alloc((size_t)64 * 4 * 1024);
  float* bs0 = (float*)alloc(256 * 4);
  float* bs1 = (float*)alloc(512 * 4);
  float* bs2 = (float*)alloc(1024 * 4);
  unsigned* wlp = (unsigned*)alloc(128 * 4);
  float* sh0 = (float*)alloc((size_t)B * H0 * 4);
  float* sc0 = (float*)alloc((size_t)B * H0 * 4);
  float* sh1 = (float*)alloc((size_t)B * H1 * 4);
  float* sc1 = (float*)alloc((size_t)B * H1 * 4);
  float* sh2 = (float*)alloc((size_t)B * H2 * 4);
  float* sc2 = (float*)alloc((size_t)B * H2 * 4);
  __half* x0 = (__half*)alloc((size_t)B * S * 32 * 2);
  __half* x1 = (__half*)alloc((size_t)B * S * H0 * 2);
  __half* x2 = (__half*)alloc((size_t)B * S * H1 * 2);
  // xh: [parity][bt(8)][half(2)] x 8KB slots
  unsigned long long* xh = (unsigned long long*)alloc((size_t)2 * 8 * 2 * 1024 * 8);
  int* cnt = (int*)alloc(8 * 2 * 32 * 4);  // padded counters (128B each)
  size_t fixed = (size_t)(p - (char*)d_ws);
  int Sc = 128;
  while (Sc > 16 && fixed + (size_t)B * Sc * 1024 * 4 > ws_size) Sc >>= 1;
  float* preT = (float*)alloc((size_t)B * Sc * 1024 * 4);

  hipMemsetAsync(cnt, 0, 8 * 2 * 32 * 4, stream);
  pack_all<<<dim3(128, 6), 256, 0, stream>>>(Whh0, Whh1, Whh2, Wih0, Wih1, Wih2,
                                             wpH0, wpH1, wpH2, wpI0, wpI1, wpI2);
  pack_misc<<<8, 256, 0, stream>>>(bih0, bhh0, bs0, bih1, bhh1, bs1,
                                   bih2, bhh2, bs2, Wl, wlp);
  f2h<<<(B * S * 32 / 8 + 255) / 256, 256, 0, stream>>>(noise, x0, B * S * 32 / 8);

  for (int c = 0; c < S / Sc; ++c) {
    int t0 = c * Sc;
    ingemm_mfma<1><<<dim3(16, Sc / 8, 1), 256, 0, stream>>>(x0, wpI0, bs0,
                                                            (f32x4*)preT, 16, Sc, t0);
    scan_s1<64><<<16, 512, 0, stream>>>(wpH0, (const f32x4*)preT, x1, sh0, sc0,
                                        Sc, t0, c == 0);
    ingemm_mfma<2><<<dim3(16, Sc / 8, 2), 256, 0, stream>>>(x1, wpI1, bs1,
                                                            (f32x4*)preT, 32, Sc, t0);
    scan_s1<128><<<16, 512, 0, stream>>>(wpH1, (const f32x4*)preT, x2, sh1, sc1,
                                         Sc, t0, c == 0);
    ingemm_mfma<4><<<dim3(16, Sc / 8, 4), 256, 0, stream>>>(x2, wpI2, bs2,
                                                            (f32x4*)preT, 64, Sc, t0);
    scan2_pair<<<16, 1024, 0, stream>>>(wpH2, (const f32x4*)preT, out, wlp, bl,
                                        sh2, sc2, xh, cnt, Sc, t0, c == 0);
  }
}

// Round 9
// 9444.543 us; speedup vs baseline: 1.0275x; 1.0275x over previous
//
#include <hip/hip_runtime.h>
#include <hip/hip_fp16.h>

#define DEVINL __device__ __forceinline__

constexpr int B = 256, S = 512;
constexpr int H0 = 64, H1 = 128, H2 = 256;

typedef _Float16 f16x8 __attribute__((ext_vector_type(8)));
typedef float f32x4 __attribute__((ext_vector_type(4)));
typedef _Float16 h2v __attribute__((ext_vector_type(2)));

DEVINL float fexp2(float x) { return __builtin_amdgcn_exp2f(x); }
DEVINL float frcp(float x) { return __builtin_amdgcn_rcpf(x); }
DEVINL float fsig(float x) { return frcp(1.f + fexp2(-1.44269504088896f * x)); }
DEVINL float ftanh_(float x) { return 1.f - 2.f * frcp(1.f + fexp2(2.88539008177793f * x)); }
DEVINL h2v as_h2(unsigned u) { union { unsigned u; h2v h; } x; x.u = u; return x.h; }
DEVINL float fdot2(unsigned a, unsigned b, float c) {
  return __builtin_amdgcn_fdot2(as_h2(a), as_h2(b), c, false);
}
union FU { uint4 u; f16x8 h; };
DEVINL f16x8 as_f16x8(uint4 u) { FU x; x.u = u; return x.h; }

DEVINL void pin(uint4& v) {
  asm volatile("" : "+v"(v.x), "+v"(v.y), "+v"(v.z), "+v"(v.w));
}
// LDS-only workgroup barrier: no vmcnt drain, global ops stay in flight.
DEVINL void wg_barrier() {
  asm volatile("s_waitcnt lgkmcnt(0)" ::: "memory");
  __builtin_amdgcn_s_barrier();
  asm volatile("" ::: "memory");
}
DEVINL void vm_drain() { asm volatile("s_waitcnt vmcnt(0)" ::: "memory"); }

// Row permutation: r' = mt*16 + quad*4 + reg -> channel = r'>>2, gate = r'&3.
// orig torch row = gate*Hch + channel. One C-frag lane holds one channel's
// (i,f,g,o) quad (C: col=lane&15, row=(lane>>4)*4+reg).

__global__ __launch_bounds__(256) void pack_all(
    const float* __restrict__ s0, const float* __restrict__ s1,
    const float* __restrict__ s2, const float* __restrict__ s3,
    const float* __restrict__ s4, const float* __restrict__ s5,
    uint4* __restrict__ d0, uint4* __restrict__ d1, uint4* __restrict__ d2,
    uint4* __restrict__ d3, uint4* __restrict__ d4, uint4* __restrict__ d5) {
  const float* src; uint4* dst; int Hch, Kdim, MT, KT;
  switch (blockIdx.y) {
    case 0: src = s0; dst = d0; Hch = 64;  Kdim = 64;  MT = 16; KT = 2; break;
    case 1: src = s1; dst = d1; Hch = 128; Kdim = 128; MT = 32; KT = 4; break;
    case 2: src = s2; dst = d2; Hch = 256; Kdim = 256; MT = 64; KT = 8; break;
    case 3: src = s3; dst = d3; Hch = 64;  Kdim = 32;  MT = 16; KT = 1; break;
    case 4: src = s4; dst = d4; Hch = 128; Kdim = 64;  MT = 32; KT = 2; break;
    default: src = s5; dst = d5; Hch = 256; Kdim = 128; MT = 64; KT = 4; break;
  }
  int o = blockIdx.x * 256 + threadIdx.x;
  if (o >= MT * KT * 64) return;
  int lane = o & 63, fk = o >> 6;
  int kt = fk % KT, mt = fk / KT;
  int rp = mt * 16 + (lane & 15);
  int orig = (rp & 3) * Hch + (rp >> 2);
  int k0 = kt * 32 + (lane >> 4) * 8;
  unsigned r[4];
#pragma unroll
  for (int p = 0; p < 4; ++p) {
    unsigned lo = __half_as_ushort(__float2half_rn(src[(size_t)orig * Kdim + k0 + 2 * p]));
    unsigned hi = __half_as_ushort(__float2half_rn(src[(size_t)orig * Kdim + k0 + 2 * p + 1]));
    r[p] = lo | (hi << 16);
  }
  uint4 v; v.x = r[0]; v.y = r[1]; v.z = r[2]; v.w = r[3];
  dst[o] = v;
}

__global__ __launch_bounds__(256) void pack_misc(
    const float* __restrict__ bih0, const float* __restrict__ bhh0, float* __restrict__ bs0,
    const float* __restrict__ bih1, const float* __restrict__ bhh1, float* __restrict__ bs1,
    const float* __restrict__ bih2, const float* __restrict__ bhh2, float* __restrict__ bs2,
    const float* __restrict__ wl, unsigned* __restrict__ wlp) {
  int i = blockIdx.x * 256 + threadIdx.x;
  if (i < 256) {
    int orig = (i & 3) * 64 + (i >> 2);
    bs0[i] = bih0[orig] + bhh0[orig];
  } else if (i < 768) {
    int r = i - 256, orig = (r & 3) * 128 + (r >> 2);
    bs1[r] = bih1[orig] + bhh1[orig];
  } else if (i < 1792) {
    int r = i - 768, orig = (r & 3) * 256 + (r >> 2);
    bs2[r] = bih2[orig] + bhh2[orig];
  } else if (i < 1920) {
    int r = i - 1792;
    unsigned lo = __half_as_ushort(__float2half_rn(wl[2 * r]));
    unsigned hi = __half_as_ushort(__float2half_rn(wl[2 * r + 1]));
    wlp[r] = lo | (hi << 16);
  }
}

__global__ __launch_bounds__(256) void f2h(const float* __restrict__ x,
                                           __half* __restrict__ y, int n8) {
  int i = blockIdx.x * 256 + threadIdx.x;
  if (i >= n8) return;
  float4 a = *(const float4*)(x + i * 8);
  float4 b = *(const float4*)(x + i * 8 + 4);
  __half h[8];
  h[0] = __float2half_rn(a.x); h[1] = __float2half_rn(a.y);
  h[2] = __float2half_rn(a.z); h[3] = __float2half_rn(a.w);
  h[4] = __float2half_rn(b.x); h[5] = __float2half_rn(b.y);
  h[6] = __float2half_rn(b.z); h[7] = __float2half_rn(b.w);
  *(uint4*)(y + i * 8) = *(const uint4*)h;
}

// MFMA input GEMM -> preT in C-frag layout.
template <int KT>
__global__ __launch_bounds__(256) __attribute__((amdgpu_waves_per_eu(4, 4)))
void ingemm_mfma(const __half* __restrict__ x,
    const uint4* __restrict__ wp, const float* __restrict__ bs,
    f32x4* __restrict__ preT, int MT, int Sc, int t0) {
  constexpr int K = KT * 32;
  const int tid = threadIdx.x, w = tid >> 6, lane = tid & 63;
  const int n16 = lane & 15, quad = lane >> 4;
  const int bt = blockIdx.x, b0 = bt * 16;
  const int tlb = blockIdx.y * 8;
  const int mb = blockIdx.z * 16;

  uint4 areg[4][KT];
#pragma unroll
  for (int im = 0; im < 4; ++im)
#pragma unroll
    for (int kt = 0; kt < KT; ++kt) {
      areg[im][kt] = wp[((size_t)(mb + w * 4 + im) * KT + kt) * 64 + lane];
      pin(areg[im][kt]);
    }
  f32x4 bini[4];
#pragma unroll
  for (int im = 0; im < 4; ++im)
    bini[im] = *(const f32x4*)(bs + (mb + w * 4 + im) * 16 + quad * 4);

  for (int tt = 0; tt < 8; ++tt) {
    int t = t0 + tlb + tt;
    const __half* xr = x + ((size_t)(b0 + n16) * S + t) * K + quad * 8;
    uint4 bfr[KT];
#pragma unroll
    for (int kt = 0; kt < KT; ++kt) bfr[kt] = *(const uint4*)(xr + kt * 32);
    f32x4 acc[4];
#pragma unroll
    for (int im = 0; im < 4; ++im) acc[im] = bini[im];
#pragma unroll
    for (int kt = 0; kt < KT; ++kt)
#pragma unroll
      for (int im = 0; im < 4; ++im)
        acc[im] = __builtin_amdgcn_mfma_f32_16x16x32_f16(as_f16x8(areg[im][kt]),
                                                         as_f16x8(bfr[kt]), acc[im], 0, 0, 0);
#pragma unroll
    for (int im = 0; im < 4; ++im)
      preT[((size_t)(bt * Sc + tlb + tt) * MT + mb + w * 4 + im) * 64 + lane] = acc[im];
  }
}

// Single-WG weight-stationary scan (layers 0/1). 16 WGs x 16 batch, 512 thr.
template <int H>
__global__ __launch_bounds__(512) __attribute__((amdgpu_waves_per_eu(2, 2)))
void scan_s1(const uint4* __restrict__ wp, const f32x4* __restrict__ preT,
             __half* __restrict__ xout, float* __restrict__ sth,
             float* __restrict__ stc, int Sc, int t0, int first) {
  constexpr int MT = H / 4;
  constexpr int MTW = MT / 8;
  constexpr int KT = H / 32;
  constexpr int HP = H + 8;
  __shared__ __half hbo[2][16 * HP];
  const int tid = threadIdx.x, w = tid >> 6, lane = tid & 63;
  const int n16 = lane & 15, quad = lane >> 4;
  const int bt = blockIdx.x, b0 = bt * 16;

  uint4 areg[MTW][KT];
#pragma unroll
  for (int im = 0; im < MTW; ++im)
#pragma unroll
    for (int kt = 0; kt < KT; ++kt) {
      areg[im][kt] = wp[((size_t)(w * MTW + im) * KT + kt) * 64 + lane];
      pin(areg[im][kt]);
    }

  float cst[MTW];
#pragma unroll
  for (int im = 0; im < MTW; ++im) {
    int ch = (w * MTW + im) * 4 + quad;
    cst[im] = first ? 0.f : stc[(size_t)(b0 + n16) * H + ch];
  }
  {
    int pi = (t0 - 1) & 1;
    for (int i = tid; i < 16 * H; i += 512) {
      int n = i / H, c = i % H;
      hbo[pi][n * HP + c] = first ? __float2half_rn(0.f)
                                  : __float2half_rn(sth[(size_t)(b0 + n) * H + c]);
    }
  }
  __syncthreads();

  f32x4 nxt[MTW];
#pragma unroll
  for (int im = 0; im < MTW; ++im)
    nxt[im] = preT[((size_t)(bt * Sc) * MT + w * MTW + im) * 64 + lane];

  for (int tl = 0; tl < Sc; ++tl) {
    const int s = t0 + tl;
    const int pw = s & 1, pbl = pw ^ 1;
    f32x4 acc[MTW];
#pragma unroll
    for (int im = 0; im < MTW; ++im) acc[im] = nxt[im];
    if (tl + 1 < Sc) {
#pragma unroll
      for (int im = 0; im < MTW; ++im)
        nxt[im] = preT[((size_t)(bt * Sc + tl + 1) * MT + w * MTW + im) * 64 + lane];
    }

#pragma unroll
    for (int kt = 0; kt < KT; ++kt) {
      uint4 bf = *(const uint4*)&hbo[pbl][n16 * HP + kt * 32 + quad * 8];
#pragma unroll
      for (int im = 0; im < MTW; ++im)
        acc[im] = __builtin_amdgcn_mfma_f32_16x16x32_f16(as_f16x8(areg[im][kt]),
                                                         as_f16x8(bf), acc[im], 0, 0, 0);
    }

    if (tl > 0 && tid < 16 * (H / 8)) {
      int n = tid / (H / 8), kq = tid % (H / 8);
      uint4 v = *(const uint4*)&hbo[pbl][n * HP + kq * 8];
      *(uint4*)(xout + ((size_t)(b0 + n) * S + (s - 1)) * H + kq * 8) = v;
    }

#pragma unroll
    for (int im = 0; im < MTW; ++im) {
      float gi = fsig(acc[im][0]);
      float gf = fsig(acc[im][1]);
      float gg = ftanh_(acc[im][2]);
      float go = fsig(acc[im][3]);
      float cn = gf * cst[im] + gi * gg;
      cst[im] = cn;
      hbo[pw][n16 * HP + (w * MTW + im) * 4 + quad] = __float2half_rn(go * ftanh_(cn));
    }
    wg_barrier();
  }

  {
    const int sl = t0 + Sc - 1, pl = sl & 1;
    if (tid < 16 * (H / 8)) {
      int n = tid / (H / 8), kq = tid % (H / 8);
      uint4 v = *(const uint4*)&hbo[pl][n * HP + kq * 8];
      *(uint4*)(xout + ((size_t)(b0 + n) * S + sl) * H + kq * 8) = v;
    }
    for (int i = tid; i < 16 * H; i += 512) {
      int n = i / H, c = i % H;
      sth[(size_t)(b0 + n) * H + c] = __half2float(hbo[pl][n * HP + c]);
    }
#pragma unroll
    for (int im = 0; im < MTW; ++im) {
      int ch = (w * MTW + im) * 4 + quad;
      stc[(size_t)(b0 + n16) * H + ch] = cst[im];
    }
  }
}

// Layer-2 scan, pipelined cross-WG exchange over 4 batch groups.
// 8 WGs = 4 pairs (pr = blk&3, half = blk>>2) x 512 thr (8 waves, 2/EU ->
// 256-reg budget). Each WG owns half the m-dim for 4 groups (64 batch cols).
// A time-step = 4 phases (one group each). Group g's peer-h import is ISSUED
// 2 phases early (waves 0,1; relaxed 8B atomics after single-writer flag
// poll) and COMMITTED to LDS 1 phase early -> RTT hidden by other groups'
// compute. Export: wave 7, from LDS after the phase barrier, vm-drain, flag.
// One lgkm-only barrier per phase. Inner 4-phase loop fully unrolled ->
// all register arrays statically indexed (no demotion).
__global__ __launch_bounds__(512) __attribute__((amdgpu_waves_per_eu(2, 2)))
void scan2_quad(const uint4* __restrict__ wp, const f32x4* __restrict__ preT,
                float* __restrict__ out, const unsigned* __restrict__ wlp,
                const float* __restrict__ blp, float* __restrict__ sth,
                float* __restrict__ stc, unsigned long long* __restrict__ xh,
                int* __restrict__ flags, int Sc, int t0, int first) {
  constexpr int HP = 136;  // half-row: 128 ch + 8 pad (halves)
  __shared__ __half hbO[4][2][16 * HP];  // own-half h per group/parity
  __shared__ __half hbP[4][2][16 * HP];  // peer-half h
  __shared__ unsigned wls[128];

  const int tid = threadIdx.x, w = tid >> 6, lane = tid & 63;
  const int n16 = lane & 15, quad = lane >> 4;
  const int pr = blockIdx.x & 3, half = blockIdx.x >> 2;
  const int phalf = 1 - half;
  const int gm0 = half * 32 + w * 4;  // 4 m-tiles per wave

  uint4 aown[4][4], apeer[4][4];
#pragma unroll
  for (int im = 0; im < 4; ++im)
#pragma unroll
    for (int ktl = 0; ktl < 4; ++ktl) {
      aown[im][ktl] = wp[((size_t)(gm0 + im) * 8 + half * 4 + ktl) * 64 + lane];
      pin(aown[im][ktl]);
      apeer[im][ktl] = wp[((size_t)(gm0 + im) * 8 + phalf * 4 + ktl) * 64 + lane];
      pin(apeer[im][ktl]);
    }
  for (int i = tid; i < 128; i += 512) wls[i] = wlp[i];

  float cst[4][4];
#pragma unroll
  for (int g = 0; g < 4; ++g) {
    int b0g = (pr * 4 + g) * 16;
#pragma unroll
    for (int im = 0; im < 4; ++im) {
      int ch = (gm0 + im) * 4 + quad;
      cst[g][im] = first ? 0.f : stc[(size_t)(b0g + n16) * 256 + ch];
    }
  }
  {
    int p0 = (t0 - 1) & 1;
    for (int i = tid; i < 4 * 16 * 128; i += 512) {
      int g = i >> 11, r = i & 2047, col = r >> 7, c = r & 127;
      int b0g = (pr * 4 + g) * 16;
      float ho = 0.f, hp = 0.f;
      if (!first) {
        ho = sth[(size_t)(b0g + col) * 256 + half * 128 + c];
        hp = sth[(size_t)(b0g + col) * 256 + phalf * 128 + c];
      }
      hbO[g][p0][col * HP + c] = __float2half_rn(ho);
      hbP[g][p0][col * HP + c] = __float2half_rn(hp);
    }
  }
  __syncthreads();

  const float bl0 = blp[0];
  const int NPH = 4 * Sc;

  // preT ring (depth 2): slot (ph&1)
  f32x4 rg[2][4];
#pragma unroll
  for (int k = 0; k < 2; ++k) {
    int gb = pr * 4 + k;
#pragma unroll
    for (int im = 0; im < 4; ++im)
      rg[k][im] = preT[(((size_t)gb * Sc) * 64 + gm0 + im) * 64 + lane];
  }
  unsigned long long lv[2][4];  // import staging, rotated per phase parity

  for (int tl = 0; tl < Sc; ++tl) {
    const int s = t0 + tl;
    const int pw = s & 1, pbl = pw ^ 1;
#pragma unroll
    for (int g = 0; g < 4; ++g) {
      const int ph = 4 * tl + g;
      const int gb = pr * 4 + g, b0g = gb * 16;

      // (A) acc from ring
      f32x4 acc[4];
#pragma unroll
      for (int im = 0; im < 4; ++im) acc[im] = rg[g & 1][im];

      // (B) export previous phase's group (wave 7)
      if (w == 7 && ph > 0) {
        const int pg = (g + 3) & 3;
        const int ps = (g == 0) ? (s - 1) : s;
        const int pp = ps & 1;
        unsigned long long* dst =
            xh + ((((size_t)pp * 4 + pr) * 2 + half) * 4 + pg) * 512;
#pragma unroll
        for (int j = 0; j < 8; ++j) {
          int idx = j * 64 + lane, col = idx >> 5, c4 = idx & 31;
          unsigned long long v =
              *(const unsigned long long*)&hbO[pg][pp][col * HP + c4 * 4];
          __hip_atomic_store(dst + idx, v, __ATOMIC_RELAXED, __HIP_MEMORY_SCOPE_AGENT);
        }
        vm_drain();  // data at LLC before flag
        if (lane == 0)
          __hip_atomic_store(&flags[((pr * 2 + half) * 4 + pg) * 32], ps + 1,
                             __ATOMIC_RELAXED, __HIP_MEMORY_SCOPE_AGENT);
      }

      // (C) import pipeline (waves 0,1)
      if (w <= 1) {
        {  // C1: commit import issued last phase -> LDS (consumed next phase)
          const int g1 = (g + 1) & 3;
          const int s1 = t0 + tl + ((g + 1) >> 2);
          if (ph >= 1 && ph + 1 < NPH && !(first && s1 == 0)) {
            const int par = (s1 - 1) & 1;
#pragma unroll
            for (int j = 0; j < 4; ++j) {
              int idx = w * 256 + j * 64 + lane, col = idx >> 5, c4 = idx & 31;
              *(unsigned long long*)&hbP[g1][par][col * HP + c4 * 4] =
                  lv[(g + 1) & 1][j];
            }
          }
        }
        {  // C2: poll + issue import for phase ph+2
          const int g2 = (g + 2) & 3;
          const int s2 = t0 + tl + ((g + 2) >> 2);
          if (ph + 2 < NPH && !(first && s2 == 0)) {
            while (__hip_atomic_load(&flags[((pr * 2 + phalf) * 4 + g2) * 32],
                                     __ATOMIC_RELAXED, __HIP_MEMORY_SCOPE_AGENT) < s2)
              __builtin_amdgcn_s_sleep(1);
            const unsigned long long* src =
                xh + ((((size_t)((s2 - 1) & 1) * 4 + pr) * 2 + phalf) * 4 + g2) * 512;
#pragma unroll
            for (int j = 0; j < 4; ++j) {
              int idx = w * 256 + j * 64 + lane;
              lv[g & 1][j] = __hip_atomic_load(src + idx, __ATOMIC_RELAXED,
                                               __HIP_MEMORY_SCOPE_AGENT);
            }
          }
        }
      }

      // (D) MFMA: own half (LDS) + peer half (LDS, imported 1 phase ago)
#pragma unroll
      for (int ktl = 0; ktl < 4; ++ktl) {
        uint4 bf = *(const uint4*)&hbO[g][pbl][n16 * HP + ktl * 32 + quad * 8];
#pragma unroll
        for (int im = 0; im < 4; ++im)
          acc[im] = __builtin_amdgcn_mfma_f32_16x16x32_f16(as_f16x8(aown[im][ktl]),
                                                           as_f16x8(bf), acc[im], 0, 0, 0);
      }
#pragma unroll
      for (int ktl = 0; ktl < 4; ++ktl) {
        uint4 bf = *(const uint4*)&hbP[g][pbl][n16 * HP + ktl * 32 + quad * 8];
#pragma unroll
        for (int im = 0; im < 4; ++im)
          acc[im] = __builtin_amdgcn_mfma_f32_16x16x32_f16(as_f16x8(apeer[im][ktl]),
                                                           as_f16x8(bf), acc[im], 0, 0, 0);
      }

      // (E) fused out(s-1), half0 wave2
      if (half == 0 && w == 2 && tl > 0) {
        int n = lane >> 2, seg = lane & 3;
        const unsigned* ro = (const unsigned*)&hbO[g][pbl][n * HP];
        const unsigned* rp = (const unsigned*)&hbP[g][pbl][n * HP];
        float sd = 0.f;
#pragma unroll
        for (int p2 = 0; p2 < 16; ++p2) {
          int op = seg * 16 + p2;
          sd = fdot2(ro[op], wls[op], sd);
          sd = fdot2(rp[op], wls[64 + op], sd);
        }
        sd += __shfl_xor(sd, 1); sd += __shfl_xor(sd, 2);
        if (seg == 0) out[(size_t)(b0g + n) * S + (s - 1)] = ftanh_(sd + bl0);
      }

      // (F) gates -> hbO[g][pw]
#pragma unroll
      for (int im = 0; im < 4; ++im) {
        float gi = fsig(acc[im][0]);
        float gf = fsig(acc[im][1]);
        float gg = ftanh_(acc[im][2]);
        float go = fsig(acc[im][3]);
        float cn = gf * cst[g][im] + gi * gg;
        cst[g][im] = cn;
        hbO[g][pw][n16 * HP + (w * 4 + im) * 4 + quad] = __float2half_rn(go * ftanh_(cn));
      }

      // (G) ring prefetch for phase ph+2 (clamped at chunk end)
      {
        const int g2 = (g + 2) & 3;
        int tl2 = tl + ((g + 2) >> 2);
        if (tl2 > Sc - 1) tl2 = Sc - 1;
        const int gb2 = pr * 4 + g2;
#pragma unroll
        for (int im = 0; im < 4; ++im)
          rg[g & 1][im] = preT[(((size_t)gb2 * Sc + tl2) * 64 + gm0 + im) * 64 + lane];
      }

      wg_barrier();  // (H) the only per-phase barrier (lgkm-only)
    }
  }

  // ---- tail ----
  {
    const int sl = t0 + Sc - 1, pl = sl & 1;
    // export last group (g=3, step sl)
    if (w == 7) {
      unsigned long long* dst = xh + ((((size_t)pl * 4 + pr) * 2 + half) * 4 + 3) * 512;
#pragma unroll
      for (int j = 0; j < 8; ++j) {
        int idx = j * 64 + lane, col = idx >> 5, c4 = idx & 31;
        unsigned long long v = *(const unsigned long long*)&hbO[3][pl][col * HP + c4 * 4];
        __hip_atomic_store(dst + idx, v, __ATOMIC_RELAXED, __HIP_MEMORY_SCOPE_AGENT);
      }
      vm_drain();
      if (lane == 0)
        __hip_atomic_store(&flags[((pr * 2 + half) * 4 + 3) * 32], sl + 1,
                           __ATOMIC_RELAXED, __HIP_MEMORY_SCOPE_AGENT);
    }
    // out(sl): own from LDS, peer direct from xh (half0 wave2)
    if (half == 0 && w == 2) {
      int n = lane >> 2, seg = lane & 3;
#pragma unroll
      for (int g = 0; g < 4; ++g) {
        int b0g = (pr * 4 + g) * 16;
        while (__hip_atomic_load(&flags[((pr * 2 + 1) * 4 + g) * 32], __ATOMIC_RELAXED,
                                 __HIP_MEMORY_SCOPE_AGENT) < sl + 1)
          __builtin_amdgcn_s_sleep(1);
        const unsigned long long* src =
            xh + ((((size_t)pl * 4 + pr) * 2 + 1) * 4 + g) * 512;
        const unsigned* ro = (const unsigned*)&hbO[g][pl][n * HP];
        float sd = 0.f;
#pragma unroll
        for (int j = 0; j < 8; ++j) {
          int u = seg * 8 + j;
          unsigned long long v = __hip_atomic_load(src + n * 32 + u, __ATOMIC_RELAXED,
                                                   __HIP_MEMORY_SCOPE_AGENT);
          sd = fdot2((unsigned)v, wls[64 + u * 2], sd);
          sd = fdot2((unsigned)(v >> 32), wls[64 + u * 2 + 1], sd);
          sd = fdot2(ro[seg * 16 + 2 * j], wls[seg * 16 + 2 * j], sd);
          sd = fdot2(ro[seg * 16 + 2 * j + 1], wls[seg * 16 + 2 * j + 1], sd);
        }
        sd += __shfl_xor(sd, 1); sd += __shfl_xor(sd, 2);
        if (seg == 0) out[(size_t)(b0g + n) * S + sl] = ftanh_(sd + bl0);
      }
    }
    // state carry (own half)
    for (int i = tid; i < 4 * 16 * 128; i += 512) {
      int g = i >> 11, r = i & 2047, col = r >> 7, c = r & 127;
      int b0g = (pr * 4 + g) * 16;
      sth[(size_t)(b0g + col) * 256 + half * 128 + c] =
          __half2float(hbO[g][pl][col * HP + c]);
    }
#pragma unroll
    for (int g = 0; g < 4; ++g) {
      int b0g = (pr * 4 + g) * 16;
#pragma unroll
      for (int im = 0; im < 4; ++im) {
        int ch = (gm0 + im) * 4 + quad;
        stc[(size_t)(b0g + n16) * 256 + ch] = cst[g][im];
      }
    }
  }
}

extern "C" void kernel_launch(void* const* d_in, const int* in_sizes, int n_in,
                              void* d_out, int out_size, void* d_ws, size_t ws_size,
                              hipStream_t stream) {
  (void)in_sizes; (void)n_in; (void)out_size;
  const float* noise = (const float*)d_in[0];
  const float* Wih0 = (const float*)d_in[1];
  const float* Whh0 = (const float*)d_in[2];
  const float* bih0 = (const float*)d_in[3];
  const float* bhh0 = (const float*)d_in[4];
  const float* Wih1 = (const float*)d_in[5];
  const float* Whh1 = (const float*)d_in[6];
  const float* bih1 = (const float*)d_in[7];
  const float* bhh1 = (const float*)d_in[8];
  const float* Wih2 = (const float*)d_in[9];
  const float* Whh2 = (const float*)d_in[10];
  const float* bih2 = (const float*)d_in[11];
  const float* bhh2 = (const float*)d_in[12];
  const float* Wl = (const float*)d_in[13];
  const float* bl = (const float*)d_in[14];
  float* out = (float*)d_out;

  char* p = (char*)d_ws;
  auto alloc = [&](size_t bytes) {
    char* r = p;
    p += (bytes + 255) & ~(size_t)255;
    return r;
  };
  uint4* wpH0 = (uint4*)alloc((size_t)16 * 2 * 1024);
  uint4* wpH1 = (uint4*)alloc((size_t)32 * 4 * 1024);
  uint4* wpH2 = (uint4*)alloc((size_t)64 * 8 * 1024);
  uint4* wpI0 = (uint4*)alloc((size_t)16 * 1 * 1024);
  uint4* wpI1 = (uint4*)alloc((size_t)32 * 2 * 1024);
  uint4* wpI2 = (uint4*)alloc((size_t)64 * 4 * 1024);
  float* bs0 = (float*)alloc(256 * 4);
  float* bs1 = (float*)alloc(512 * 4);
  float* bs2 = (float*)alloc(1024 * 4);
  unsigned* wlp = (unsigned*)alloc(128 * 4);
  float* sh0 = (float*)alloc((size_t)B * H0 * 4);
  float* sc0 = (float*)alloc((size_t)B * H0 * 4);
  float* sh1 = (float*)alloc((size_t)B * H1 * 4);
  float* sc1 = (float*)alloc((size_t)B * H1 * 4);
  float* sh2 = (float*)alloc((size_t)B * H2 * 4);
  float* sc2 = (float*)alloc((size_t)B * H2 * 4);
  __half* x0 = (__half*)alloc((size_t)B * S * 32 * 2);
  __half* x1 = (__half*)alloc((size_t)B * S * H0 * 2);
  __half* x2 = (__half*)alloc((size_t)B * S * H1 * 2);
  // xh: [parity(2)][pair(4)][half(2)][group(4)] x 4KB slots
  unsigned long long* xh = (unsigned long long*)alloc((size_t)2 * 4 * 2 * 4 * 512 * 8);
  int* flags = (int*)alloc(4 * 2 * 4 * 32 * 4);  // 128B-padded, single-writer
  size_t fixed = (size_t)(p - (char*)d_ws);
  int Sc = 128;
  while (Sc > 16 && fixed + (size_t)B * Sc * 1024 * 4 > ws_size) Sc >>= 1;
  float* preT = (float*)alloc((size_t)B * Sc * 1024 * 4);

  hipMemsetAsync(flags, 0, 4 * 2 * 4 * 32 * 4, stream);
  pack_all<<<dim3(128, 6), 256, 0, stream>>>(Whh0, Whh1, Whh2, Wih0, Wih1, Wih2,
                                             wpH0, wpH1, wpH2, wpI0, wpI1, wpI2);
  pack_misc<<<8, 256, 0, stream>>>(bih0, bhh0, bs0, bih1, bhh1, bs1,
                                   bih2, bhh2, bs2, Wl, wlp);
  f2h<<<(B * S * 32 / 8 + 255) / 256, 256, 0, stream>>>(noise, x0, B * S * 32 / 8);

  for (int c = 0; c < S / Sc; ++c) {
    int t0 = c * Sc;
    ingemm_mfma<1><<<dim3(16, Sc / 8, 1), 256, 0, stream>>>(x0, wpI0, bs0,
                                                            (f32x4*)preT, 16, Sc, t0);
    scan_s1<64><<<16, 512, 0, stream>>>(wpH0, (const f32x4*)preT, x1, sh0, sc0,
                                        Sc, t0, c == 0);
    ingemm_mfma<2><<<dim3(16, Sc / 8, 2), 256, 0, stream>>>(x1, wpI1, bs1,
                                                            (f32x4*)preT, 32, Sc, t0);
    scan_s1<128><<<16, 512, 0, stream>>>(wpH1, (const f32x4*)preT, x2, sh1, sc1,
                                         Sc, t0, c == 0);
    ingemm_mfma<4><<<dim3(16, Sc / 8, 4), 256, 0, stream>>>(x2, wpI2, bs2,
                                                            (f32x4*)preT, 64, Sc, t0);
    scan2_quad<<<8, 512, 0, stream>>>(wpH2, (const f32x4*)preT, out, wlp, bl,
                                      sh2, sc2, xh, flags, Sc, t0, c == 0);
  }
}